// Round 1
// baseline (429.240 us; speedup 1.0000x reference)
//
#include <hip/hip_runtime.h>

// DisplacementVectorsASU: out[i] = frac[e0[i]] - wrap(symmops[i] @ [frac[e1[i]],1])[:3] - ct[i]
// with wrap(x) = x - floor(x) + ct (per reference).
// Memory-bound: ~384 MB traffic per launch -> ~61 us roofline at 6.3 TB/s.

__global__ __launch_bounds__(256) void disp_vec_kernel(
    const float* __restrict__ frac,      // (N,3)
    const int*   __restrict__ eidx,      // (2,M)
    const float* __restrict__ symm,      // (M,4,4)
    const float* __restrict__ ct,        // (M,3)
    float*       __restrict__ out,       // (M,3)
    int M)
{
    int i = blockIdx.x * blockDim.x + threadIdx.x;
    if (i >= M) return;

    int n0 = eidx[i];        // in node
    int n1 = eidx[M + i];    // out node

    // gather node coords (1.2 MB table -> L2-resident)
    const float* f0 = frac + (size_t)n0 * 3;
    const float* f1 = frac + (size_t)n1 * 3;
    float in_x = f0[0], in_y = f0[1], in_z = f0[2];
    float ox   = f1[0], oy   = f1[1], oz   = f1[2];

    // symmop rows 0..2 (row 3 unused). 64B-aligned block -> float4 loads.
    const float4* s = (const float4*)(symm + (size_t)i * 16);
    float4 r0 = s[0];
    float4 r1 = s[1];
    float4 r2 = s[2];

    float t0 = ox * r0.x + oy * r0.y + oz * r0.z + r0.w;
    float t1 = ox * r1.x + oy * r1.y + oz * r1.z + r1.w;
    float t2 = ox * r2.x + oy * r2.y + oz * r2.z + r2.w;

    t0 -= floorf(t0);
    t1 -= floorf(t1);
    t2 -= floorf(t2);

    const float* c = ct + (size_t)i * 3;
    t0 += c[0];
    t1 += c[1];
    t2 += c[2];

    float* o = out + (size_t)i * 3;
    o[0] = in_x - t0;
    o[1] = in_y - t1;
    o[2] = in_z - t2;
}

extern "C" void kernel_launch(void* const* d_in, const int* in_sizes, int n_in,
                              void* d_out, int out_size, void* d_ws, size_t ws_size,
                              hipStream_t stream) {
    const float* frac = (const float*)d_in[0];   // (100000, 3) f32
    const int*   eidx = (const int*)d_in[1];     // (2, 4000000) i32
    const float* symm = (const float*)d_in[2];   // (4000000, 4, 4) f32
    const float* ct   = (const float*)d_in[3];   // (4000000, 3) f32
    float* out = (float*)d_out;                  // (4000000, 3) f32

    const int M = in_sizes[1] / 2;               // 4,000,000 edges

    const int block = 256;
    const int grid = (M + block - 1) / block;
    disp_vec_kernel<<<grid, block, 0, stream>>>(frac, eidx, symm, ct, out, M);
}